// Round 1
// baseline (527.614 us; speedup 1.0000x reference)
//
#include <hip/hip_runtime.h>
#include <math.h>

#define Lseq 2048
// B=16, H=8, E=64, O=64, MODES=64

// ---------------- workspace layout (bytes) ----------------
// twq  [2048][64] float2   1 MB   DFT twiddles for q (freq = index_q)
// twk  [2048][64] float2   1 MB   DFT twiddles for k (freq = index_kv)
// twi  [64][2048] float2   1 MB   iDFT twiddles (freq = index_q), transposed
// Gq   [16][8][64][64] f2  4 MB   raw-q DFT (pre-projection)
// Gk   [16][8][64][64] f2  4 MB
// U    [16][8][64][64] f2  4 MB   post-attention, pre-weights
// A    [16][8][64][64] f2  4 MB   (P,Q) irfft coefficients, scales folded
// wc   [8][64][64][64] f2 16 MB   transposed complex weights [h][x][e][o]
#define OFF_TWQ (0u)
#define OFF_TWK (1u << 20)
#define OFF_TWI (2u << 20)
#define OFF_GQ  (3u << 20)
#define OFF_GK  (7u << 20)
#define OFF_U   (11u << 20)
#define OFF_A   (15u << 20)
#define OFF_WC  (19u << 20)

// ---------------------------------------------------------------------------
// Twiddle tables. Exact integer phase mod 2048 keeps the DFT periodic-exact.
__global__ __launch_bounds__(256) void k_twiddle(
    const int* __restrict__ iq, const int* __restrict__ ikv,
    float2* __restrict__ twq, float2* __restrict__ twk, float2* __restrict__ twi)
{
    int idx = blockIdx.x * 256 + threadIdx.x;   // 0 .. 2048*64-1
    int t = idx >> 6;
    int m = idx & 63;
    const float w = 6.2831853071795864769f / (float)Lseq;
    int fq = iq[m];
    int ph = (t * fq) & (Lseq - 1);
    float s, c;
    sincosf(w * (float)ph, &s, &c);
    twq[idx] = make_float2(c, s);
    twi[m * Lseq + t] = make_float2(c, s);      // irfft table, [m][t]
    int fk = ikv[m];
    ph = (t * fk) & (Lseq - 1);
    sincosf(w * (float)ph, &s, &c);
    twk[idx] = make_float2(c, s);
}

// ---------------------------------------------------------------------------
// Transpose weights to wc[h][x][e][o] = (w1[h][e][o][x], w2[h][e][o][x])
// so the per-(h,x) contraction kernel reads a contiguous 32 KB block.
__global__ __launch_bounds__(256) void k_wtrans(
    const float* __restrict__ w1, const float* __restrict__ w2,
    float2* __restrict__ wc)
{
    int h = blockIdx.x, e = blockIdx.y;
    const float* p1 = w1 + (((size_t)h * 64 + e) * 64) * 64;  // [o][x]
    const float* p2 = w2 + (((size_t)h * 64 + e) * 64) * 64;
    __shared__ float s1[64][65];   // +1 pad: conflict-free transposed reads
    __shared__ float s2[64][65];
    int tid = threadIdx.x;
    for (int i = tid; i < 1024; i += 256) {      // 1024 float4 per array
        int o = i >> 4, xc = (i & 15) * 4;
        float4 a = *(const float4*)(p1 + o * 64 + xc);
        s1[o][xc] = a.x; s1[o][xc + 1] = a.y; s1[o][xc + 2] = a.z; s1[o][xc + 3] = a.w;
        float4 b = *(const float4*)(p2 + o * 64 + xc);
        s2[o][xc] = b.x; s2[o][xc + 1] = b.y; s2[o][xc + 2] = b.z; s2[o][xc + 3] = b.w;
    }
    __syncthreads();
    float2* dst = wc + ((size_t)h * 64) * 4096 + (size_t)e * 64;
    for (int i = tid; i < 4096; i += 256) {
        int x = i >> 6, o = i & 63;
        dst[(size_t)x * 4096 + o] = make_float2(s1[o][x], s2[o][x]);
    }
}

// ---------------------------------------------------------------------------
// Partial DFT of raw q/k (pre-projection): per block (b, h, tensor) compute
// G[e, m] = sum_t x[b,t,h,e] * (cos, -sin)(2*pi*freq[m]*t/L).
// GEMM [64 e x 2048 t] @ [2048 t x 128 (cos|sin interleaved)].
// 512 threads = 4 k-groups x 128; each k-group owns 512 t, reduced at end.
__global__ __launch_bounds__(512) void k_dft(
    const float* __restrict__ q, const float* __restrict__ k,
    const float* __restrict__ twq, const float* __restrict__ twk,
    float2* __restrict__ Gq, float2* __restrict__ Gk)
{
    int b = blockIdx.x, h = blockIdx.y, z = blockIdx.z;
    const float* src = (z == 0) ? q : k;
    const float* tws = (z == 0) ? twq : twk;
    float2* gdst = ((z == 0) ? Gq : Gk) + (size_t)(b * 8 + h) * 4096;

    // union: staging (48 KB) reused as reduction buffer (32 KB)
    __shared__ float sm[12288];
    float* q_s  = sm;          // [4][16][64]
    float* tw_s = sm + 4096;   // [4][16][128]

    int tid = threadIdx.x;
    int kg = tid >> 7;          // k-group 0..3
    int tl = tid & 127;
    int heg = tl >> 4;          // 0..7  -> e0 = heg*8
    int cg  = tl & 15;          // 0..15 -> c0 = cg*8

    const float* qbase = src + ((size_t)b * Lseq) * 512 + h * 64;

    float acc[8][8];
#pragma unroll
    for (int i = 0; i < 8; ++i)
#pragma unroll
        for (int j = 0; j < 8; ++j) acc[i][j] = 0.f;

    for (int tb = kg * 512; tb < kg * 512 + 512; tb += 16) {
        // stage q rows: 16 x 64 floats (256 float4, 128 threads x 2)
#pragma unroll
        for (int j = 0; j < 2; ++j) {
            int fl = tl + 128 * j;
            int r = fl >> 4, c4 = fl & 15;
            *(float4*)&q_s[kg * 1024 + r * 64 + c4 * 4] =
                *(const float4*)(qbase + (size_t)(tb + r) * 512 + c4 * 4);
        }
        // stage twiddle rows: 16 x 128 floats (512 float4, 128 threads x 4)
#pragma unroll
        for (int j = 0; j < 4; ++j) {
            int fl = tl + 128 * j;
            int r = fl >> 5, c4 = fl & 31;
            *(float4*)&tw_s[kg * 2048 + r * 128 + c4 * 4] =
                *(const float4*)(tws + (size_t)(tb + r) * 128 + c4 * 4);
        }
        __syncthreads();
#pragma unroll
        for (int r = 0; r < 16; ++r) {
            float av[8], bv[8];
            *(float4*)&av[0] = *(float4*)&q_s[kg * 1024 + r * 64 + heg * 8];
            *(float4*)&av[4] = *(float4*)&q_s[kg * 1024 + r * 64 + heg * 8 + 4];
            *(float4*)&bv[0] = *(float4*)&tw_s[kg * 2048 + r * 128 + cg * 8];
            *(float4*)&bv[4] = *(float4*)&tw_s[kg * 2048 + r * 128 + cg * 8 + 4];
#pragma unroll
            for (int i = 0; i < 8; ++i)
#pragma unroll
                for (int j = 0; j < 8; ++j)
                    acc[i][j] += av[i] * bv[j];
        }
        __syncthreads();
    }

    // cross-k-group reduction into sm (reuse as red[64][128])
    float* red = sm;
    for (int round = 0; round < 4; ++round) {
        if (kg == round) {
#pragma unroll
            for (int i = 0; i < 8; ++i)
#pragma unroll
                for (int j = 0; j < 8; ++j) {
                    int off = (heg * 8 + i) * 128 + cg * 8 + j;
                    if (round == 0) red[off] = acc[i][j];
                    else            red[off] += acc[i][j];
                }
        }
        __syncthreads();
    }
    // store G = (sum cos, -sum sin)  [rfft sign]
    const float2* r2 = (const float2*)red;
#pragma unroll
    for (int j = 0; j < 8; ++j) {
        int idx = tid + 512 * j;   // e*64+x
        float2 v = r2[idx];
        gdst[idx] = make_float2(v.x, -v.y);
    }
}

// ---------------------------------------------------------------------------
// Per (b,h): freq-domain projection of q,k; S = Q^T K (complex, no conj);
// tanh per part; U[e,x] = sum_y T[x,y] K[e,y]. 256 threads, ~115 KB LDS.
__global__ __launch_bounds__(256) void k_core(
    const float2* __restrict__ Gq, const float2* __restrict__ Gk,
    const float* __restrict__ wqw, const float* __restrict__ wqb,
    const float* __restrict__ wkw, const float* __restrict__ wkb,
    const int* __restrict__ iq, const int* __restrict__ ikv,
    float2* __restrict__ U)
{
    int b = blockIdx.x, h = blockIdx.y;
    int tid = threadIdx.x;
    __shared__ float2 bufA[4096];   // G load, later T[y][x]
    __shared__ float2 Qf[4096];     // [e][x]
    __shared__ float2 Kf[4096];     // [e][y]
    __shared__ float  Wm[4096];
    __shared__ float  bias_s[64];
    __shared__ int    idx_s[64];

    size_t gb = (size_t)(b * 8 + h) * 4096;

    // ---- projection for q (z=0) then k (z=1) ----
    for (int z = 0; z < 2; ++z) {
        const float* Wsrc = z ? wkw : wqw;
        const float* bsrc = z ? wkb : wqb;
        const int*   isrc = z ? ikv : iq;
        const float2* Gsrc = (z ? Gk : Gq) + gb;
        float2* dst = z ? Kf : Qf;
        if (tid < 64) { bias_s[tid] = bsrc[tid]; idx_s[tid] = isrc[tid]; }
#pragma unroll
        for (int j = 0; j < 4; ++j)
            ((float4*)Wm)[tid + 256 * j] = ((const float4*)Wsrc)[tid + 256 * j];
#pragma unroll
        for (int j = 0; j < 8; ++j)
            ((float4*)bufA)[tid + 256 * j] = ((const float4*)Gsrc)[tid + 256 * j];
        __syncthreads();
        {
            int eg = tid >> 4, xg = tid & 15;
            float2 acc[4][4];
#pragma unroll
            for (int i = 0; i < 4; ++i)
#pragma unroll
                for (int j = 0; j < 4; ++j) acc[i][j] = make_float2(0.f, 0.f);
            for (int ep = 0; ep < 64; ++ep) {
                float wv[4]; float2 gv[4];
#pragma unroll
                for (int i = 0; i < 4; ++i) wv[i] = Wm[(eg * 4 + i) * 64 + ep];
#pragma unroll
                for (int j = 0; j < 4; ++j) gv[j] = bufA[ep * 64 + xg + 16 * j];
#pragma unroll
                for (int i = 0; i < 4; ++i)
#pragma unroll
                    for (int j = 0; j < 4; ++j) {
                        acc[i][j].x += wv[i] * gv[j].x;
                        acc[i][j].y += wv[i] * gv[j].y;
                    }
            }
#pragma unroll
            for (int j = 0; j < 4; ++j) {
                int x = xg + 16 * j;
                float bz = (idx_s[x] == 0) ? 2048.0f : 0.0f;   // bias only at f=0
#pragma unroll
                for (int i = 0; i < 4; ++i) {
                    float2 v = acc[i][j];
                    v.x += bz * bias_s[eg * 4 + i];
                    dst[(eg * 4 + i) * 64 + x] = v;
                }
            }
        }
        __syncthreads();
    }

    // ---- S[x,y] = sum_e Qf[e,x]*Kf[e,y]; T = tanh parts -> bufA[y][x] ----
    {
        int xg = tid & 15, yg = tid >> 4;
        float2 acc[4][4];
#pragma unroll
        for (int i = 0; i < 4; ++i)
#pragma unroll
            for (int j = 0; j < 4; ++j) acc[i][j] = make_float2(0.f, 0.f);
        for (int e = 0; e < 64; ++e) {
            float2 qv[4], kv[4];
#pragma unroll
            for (int i = 0; i < 4; ++i) qv[i] = Qf[e * 64 + xg + 16 * i];
#pragma unroll
            for (int j = 0; j < 4; ++j) kv[j] = Kf[e * 64 + yg * 4 + j];
#pragma unroll
            for (int i = 0; i < 4; ++i)
#pragma unroll
                for (int j = 0; j < 4; ++j) {
                    acc[i][j].x += qv[i].x * kv[j].x - qv[i].y * kv[j].y;
                    acc[i][j].y += qv[i].x * kv[j].y + qv[i].y * kv[j].x;
                }
        }
#pragma unroll
        for (int i = 0; i < 4; ++i)
#pragma unroll
            for (int j = 0; j < 4; ++j)
                bufA[(yg * 4 + j) * 64 + xg + 16 * i] =
                    make_float2(tanhf(acc[i][j].x), tanhf(acc[i][j].y));
    }
    __syncthreads();

    // ---- U[e,x] = sum_y T[x,y] * Kf[e,y] -> global ----
    {
        int xg = tid & 15, eg = tid >> 4;
        float2 acc[4][4];
#pragma unroll
        for (int i = 0; i < 4; ++i)
#pragma unroll
            for (int j = 0; j < 4; ++j) acc[i][j] = make_float2(0.f, 0.f);
        for (int y = 0; y < 64; ++y) {
            float2 kv[4], tv[4];
#pragma unroll
            for (int i = 0; i < 4; ++i) kv[i] = Kf[(eg * 4 + i) * 64 + y];
#pragma unroll
            for (int j = 0; j < 4; ++j) tv[j] = bufA[y * 64 + xg + 16 * j];
#pragma unroll
            for (int i = 0; i < 4; ++i)
#pragma unroll
                for (int j = 0; j < 4; ++j) {
                    acc[i][j].x += tv[j].x * kv[i].x - tv[j].y * kv[i].y;
                    acc[i][j].y += tv[j].x * kv[i].y + tv[j].y * kv[i].x;
                }
        }
        float2* Ud = U + gb;
#pragma unroll
        for (int i = 0; i < 4; ++i)
#pragma unroll
            for (int j = 0; j < 4; ++j)
                Ud[(eg * 4 + i) * 64 + xg + 16 * j] = acc[i][j];
    }
}

// ---------------------------------------------------------------------------
// Per (h,x): X[b,o] = sum_e U[b,e] * wc[e,o] (complex*complex), fold irfft
// scale factors, store A[b][h][o][x] = (P, Q) with out = sum P cos + Q sin.
__global__ __launch_bounds__(128) void k_apply_w(
    const float2* __restrict__ U, const float2* __restrict__ wc,
    const int* __restrict__ iq, float2* __restrict__ A)
{
    int x = blockIdx.x, h = blockIdx.y;
    int tid = threadIdx.x;
    __shared__ float2 wl[4096];     // [e][o]
    __shared__ float2 ul[16][65];   // [b][e], padded
    const float4* wsrc = (const float4*)(wc + (size_t)(h * 64 + x) * 4096);
#pragma unroll
    for (int j = 0; j < 16; ++j)
        ((float4*)wl)[tid + 128 * j] = wsrc[tid + 128 * j];
#pragma unroll
    for (int j = 0; j < 8; ++j) {
        int idx = tid + 128 * j;     // 0..1023
        int bb = idx >> 6, e = idx & 63;
        ul[bb][e] = U[((size_t)(bb * 8 + h) * 64 + e) * 64 + x];
    }
    __syncthreads();
    int bb = tid >> 3, og = tid & 7;
    float2 acc[8];
#pragma unroll
    for (int j = 0; j < 8; ++j) acc[j] = make_float2(0.f, 0.f);
    for (int e = 0; e < 64; ++e) {
        float2 u = ul[bb][e];
#pragma unroll
        for (int j = 0; j < 8; ++j) {
            float2 wv = wl[e * 64 + og + 8 * j];
            acc[j].x += u.x * wv.x - u.y * wv.y;
            acc[j].y += u.x * wv.y + u.y * wv.x;
        }
    }
    int f = iq[x];
    bool dc = (f == 0) || (2 * f == Lseq);
    float cm = (dc ? 1.0f : 2.0f) * (1.0f / (2048.0f * 262144.0f));
    float2* Ad = A + (size_t)(bb * 8 + h) * 4096;
#pragma unroll
    for (int j = 0; j < 8; ++j) {
        int o = og + 8 * j;
        // irfft: out = ReA*cos - ImA*sin ; store (P,Q) with Q = -c*Im (0 at DC)
        Ad[o * 64 + x] = make_float2(cm * acc[j].x, dc ? 0.0f : -cm * acc[j].y);
    }
}

// ---------------------------------------------------------------------------
// 64-mode inverse DFT: out[b,h,o,t] = sum_x P[o,x]*cos + Q[o,x]*sin.
// Block = (t-tile 256, h, b); GEMM [64 o x 128] @ [128 x 256 t].
__global__ __launch_bounds__(256) void k_irfft(
    const float2* __restrict__ A, const float2* __restrict__ twi,
    float* __restrict__ out)
{
    int tt = blockIdx.x, h = blockIdx.y, b = blockIdx.z;
    int t0 = tt * 256;
    int tid = threadIdx.x;
    __shared__ float2 Al[4096];      // [o][x]
    __shared__ float2 twl[16][256];  // x-chunk of twiddles
    const float4* asrc = (const float4*)(A + (size_t)(b * 8 + h) * 4096);
#pragma unroll
    for (int j = 0; j < 8; ++j)
        ((float4*)Al)[tid + 256 * j] = asrc[tid + 256 * j];
    int og = tid >> 5, tl = tid & 31;   // o-group 0..7, t-lane 0..31
    float acc[8][8];
#pragma unroll
    for (int o = 0; o < 8; ++o)
#pragma unroll
        for (int j = 0; j < 8; ++j) acc[o][j] = 0.f;
    for (int xc = 0; xc < 4; ++xc) {
        __syncthreads();
#pragma unroll
        for (int j = 0; j < 16; ++j)
            twl[j][tid] = twi[(size_t)(xc * 16 + j) * Lseq + t0 + tid];
        __syncthreads();
#pragma unroll
        for (int xi = 0; xi < 16; ++xi) {
            int xx = xc * 16 + xi;
            float2 tw[8];
#pragma unroll
            for (int j = 0; j < 8; ++j) tw[j] = twl[xi][tl + 32 * j];
#pragma unroll
            for (int o = 0; o < 8; ++o) {
                float2 a = Al[(og * 8 + o) * 64 + xx];
#pragma unroll
                for (int j = 0; j < 8; ++j)
                    acc[o][j] += a.x * tw[j].x + a.y * tw[j].y;
            }
        }
    }
    float* op = out + ((size_t)(b * 8 + h) * 64) * Lseq + t0;
#pragma unroll
    for (int o = 0; o < 8; ++o)
#pragma unroll
        for (int j = 0; j < 8; ++j)
            op[(size_t)(og * 8 + o) * Lseq + tl + 32 * j] = acc[o][j];
}

// ---------------------------------------------------------------------------
extern "C" void kernel_launch(void* const* d_in, const int* in_sizes, int n_in,
                              void* d_out, int out_size, void* d_ws, size_t ws_size,
                              hipStream_t stream)
{
    const float* q    = (const float*)d_in[0];
    const float* k    = (const float*)d_in[1];
    // d_in[2] = v  (projected-but-unused in reference -> never read)
    const float* wq_w = (const float*)d_in[3];
    const float* wq_b = (const float*)d_in[4];
    const float* wk_w = (const float*)d_in[5];
    const float* wk_b = (const float*)d_in[6];
    // d_in[7,8] = wv_w, wv_b (unused)
    const float* w1   = (const float*)d_in[9];
    const float* w2   = (const float*)d_in[10];
    const int*   iq   = (const int*)d_in[11];
    const int*   ikv  = (const int*)d_in[12];
    float* out = (float*)d_out;

    char* ws = (char*)d_ws;
    float2* twq = (float2*)(ws + OFF_TWQ);
    float2* twk = (float2*)(ws + OFF_TWK);
    float2* twi = (float2*)(ws + OFF_TWI);
    float2* Gq  = (float2*)(ws + OFF_GQ);
    float2* Gk  = (float2*)(ws + OFF_GK);
    float2* Uw  = (float2*)(ws + OFF_U);
    float2* Aw  = (float2*)(ws + OFF_A);
    float2* wc  = (float2*)(ws + OFF_WC);

    k_twiddle<<<512, 256, 0, stream>>>(iq, ikv, twq, twk, twi);
    k_wtrans<<<dim3(8, 64), 256, 0, stream>>>(w1, w2, wc);
    k_dft<<<dim3(16, 8, 2), 512, 0, stream>>>(q, k, (const float*)twq,
                                              (const float*)twk, Gq, Gk);
    k_core<<<dim3(16, 8), 256, 0, stream>>>(Gq, Gk, wq_w, wq_b, wk_w, wk_b,
                                            iq, ikv, Uw);
    k_apply_w<<<dim3(64, 8), 128, 0, stream>>>(Uw, wc, iq, Aw);
    k_irfft<<<dim3(8, 8, 16), 256, 0, stream>>>(Aw, twi, out);
}

// Round 2
// 378.543 us; speedup vs baseline: 1.3938x; 1.3938x over previous
//
#include <hip/hip_runtime.h>
#include <math.h>

#define Lseq 2048
// B=16, H=8, E=64, O=64, MODES=64
// Radix-4 DIF decomposition: all selected freqs f < 64, f = 4g + r.
// t = t' + 512 j, t' in [0,512):  e^{-2pi i f t/2048} = tw(t',f) * (-i)^{r j}
// y0 = x0+x1+x2+x3 (r=0), y2 = x0-x1+x2-x3 (r=2), y1 = p - i q, y3 = p + i q
// with p = x0-x2, q = x1-x3  (x_j = x[t'+512 j]).

// ---------------- workspace layout (bytes) ----------------
// twq [512][64] float2  256 KB   twiddles (cos, +sin) at freq index_q
// twk [512][64] float2  256 KB   twiddles at freq index_kv
// Gq  [16][8][64][64]c    4 MB
// Gk                      4 MB
// U                       4 MB
// A                       4 MB
// Gp  [512 slots][32KB]  16 MB   split-K partials (ALIASES wc)
// wc  [8][64][64][64] f2 16 MB   built AFTER k_reduce consumed Gp
#define OFF_TWQ 0u
#define OFF_TWK (256u << 10)
#define OFF_GQ  (1u << 20)
#define OFF_GK  (5u << 20)
#define OFF_U   (9u << 20)
#define OFF_A   (13u << 20)
#define OFF_GP  (17u << 20)
#define OFF_WC  (17u << 20)

// ---------------------------------------------------------------------------
__global__ __launch_bounds__(256) void k_twiddle(
    const int* __restrict__ iq, const int* __restrict__ ikv,
    float2* __restrict__ twq, float2* __restrict__ twk)
{
    int idx = blockIdx.x * 256 + threadIdx.x;   // 0 .. 512*64-1
    int t = idx >> 6;
    int m = idx & 63;
    const float w = 6.2831853071795864769f / (float)Lseq;
    float s, c;
    int ph = (t * iq[m]) & (Lseq - 1);
    sincosf(w * (float)ph, &s, &c);
    twq[idx] = make_float2(c, s);
    ph = (t * ikv[m]) & (Lseq - 1);
    sincosf(w * (float)ph, &s, &c);
    twk[idx] = make_float2(c, s);
}

// ---------------------------------------------------------------------------
// Transpose weights to wc[h][x][e][o]
__global__ __launch_bounds__(256) void k_wtrans(
    const float* __restrict__ w1, const float* __restrict__ w2,
    float2* __restrict__ wc)
{
    int h = blockIdx.x, e = blockIdx.y;
    const float* p1 = w1 + (((size_t)h * 64 + e) * 64) * 64;  // [o][x]
    const float* p2 = w2 + (((size_t)h * 64 + e) * 64) * 64;
    __shared__ float s1[64][65];
    __shared__ float s2[64][65];
    int tid = threadIdx.x;
    for (int i = tid; i < 1024; i += 256) {
        int o = i >> 4, xc = (i & 15) * 4;
        float4 a = *(const float4*)(p1 + o * 64 + xc);
        s1[o][xc] = a.x; s1[o][xc + 1] = a.y; s1[o][xc + 2] = a.z; s1[o][xc + 3] = a.w;
        float4 b = *(const float4*)(p2 + o * 64 + xc);
        s2[o][xc] = b.x; s2[o][xc + 1] = b.y; s2[o][xc + 2] = b.z; s2[o][xc + 3] = b.w;
    }
    __syncthreads();
    float2* dst = wc + ((size_t)h * 64) * 4096 + (size_t)e * 64;
    for (int i = tid; i < 4096; i += 256) {
        int x = i >> 6, o = i & 63;
        dst[(size_t)x * 4096 + o] = make_float2(s1[o][x], s2[o][x]);
    }
}

// ---------------------------------------------------------------------------
// Radix-4 partial DFT with split-K.
// grid (b, h, zc): z = zc>>1, chunk = zc&1. 512 threads = 2 subs x 256.
// Each sub handles 128 t' (8 rounds of 16); cross-sub reduce in LDS.
// Thread (eg,g): e-tile 4, mode-quad 4g..4g+3, 48 fp32 accumulators.
__global__ __launch_bounds__(512) void k_dft(
    const float* __restrict__ q, const float* __restrict__ k,
    const float* __restrict__ twq, const float* __restrict__ twk,
    float2* __restrict__ Gp)
{
    int b = blockIdx.x, h = blockIdx.y, zc = blockIdx.z;
    int z = zc >> 1, chunk = zc & 1;
    const float* src = z ? k : q;
    const float* tws = z ? twk : twq;

    __shared__ float y_s[2][16][4][64];    // 32 KB  (reused as reduce buf)
    __shared__ float tw_s[2][16][144];     // 18 KB  bank-rotated g-slots

    int tid = threadIdx.x;
    int sub = tid >> 8;
    int st  = tid & 255;
    int eg = st >> 4, g = st & 15;         // e0 = eg*4
    int t_base = chunk * 256 + sub * 128;
    const float* xbase = src + ((size_t)b * Lseq) * 512 + h * 64;
    int goff = g * 8 + ((g >> 2) << 2);    // bank-rotated tw slot (2-way max)

    float a[4][12];
#pragma unroll
    for (int i = 0; i < 4; ++i)
#pragma unroll
        for (int j = 0; j < 12; ++j) a[i][j] = 0.f;

    for (int rnd = 0; rnd < 8; ++rnd) {
        int t0 = t_base + rnd * 16;
        {   // stage y: one float4 task per thread (16 t' x 16 e-quads)
            int tl = st >> 4, e4 = (st & 15) * 4;
            const float* p = xbase + (size_t)(t0 + tl) * 512 + e4;
            float4 v0 = *(const float4*)(p);
            float4 v1 = *(const float4*)(p + 512 * 512);
            float4 v2 = *(const float4*)(p + 1024 * 512);
            float4 v3 = *(const float4*)(p + 1536 * 512);
            float4 sa, sb, y0, y2, pp, qq;
            sa.x = v0.x + v2.x; sa.y = v0.y + v2.y; sa.z = v0.z + v2.z; sa.w = v0.w + v2.w;
            sb.x = v1.x + v3.x; sb.y = v1.y + v3.y; sb.z = v1.z + v3.z; sb.w = v1.w + v3.w;
            y0.x = sa.x + sb.x; y0.y = sa.y + sb.y; y0.z = sa.z + sb.z; y0.w = sa.w + sb.w;
            y2.x = sa.x - sb.x; y2.y = sa.y - sb.y; y2.z = sa.z - sb.z; y2.w = sa.w - sb.w;
            pp.x = v0.x - v2.x; pp.y = v0.y - v2.y; pp.z = v0.z - v2.z; pp.w = v0.w - v2.w;
            qq.x = v1.x - v3.x; qq.y = v1.y - v3.y; qq.z = v1.z - v3.z; qq.w = v1.w - v3.w;
            *(float4*)&y_s[sub][tl][0][e4] = y0;
            *(float4*)&y_s[sub][tl][1][e4] = y2;
            *(float4*)&y_s[sub][tl][2][e4] = pp;
            *(float4*)&y_s[sub][tl][3][e4] = qq;
        }
        {   // stage tw: 2 float4 tasks per thread (16 t' x 16 g x 2 halves)
#pragma unroll
            for (int u = 0; u < 2; ++u) {
                int i = st * 2 + u;
                int tl = i >> 5, rem = i & 31, gg = rem >> 1, half = rem & 1;
                float4 w = *(const float4*)(tws + (size_t)(t0 + tl) * 128 + gg * 8 + half * 4);
                *(float4*)&tw_s[sub][tl][gg * 8 + ((gg >> 2) << 2) + half * 4] = w;
            }
        }
        __syncthreads();
#pragma unroll
        for (int tt = 0; tt < 16; ++tt) {
            float4 Y0 = *(float4*)&y_s[sub][tt][0][eg * 4];
            float4 Y2 = *(float4*)&y_s[sub][tt][1][eg * 4];
            float4 Pv = *(float4*)&y_s[sub][tt][2][eg * 4];
            float4 Qv = *(float4*)&y_s[sub][tt][3][eg * 4];
            float4 w0 = *(float4*)&tw_s[sub][tt][goff];      // c0,s0,c1,s1
            float4 w1 = *(float4*)&tw_s[sub][tt][goff + 4];  // c2,s2,c3,s3
            const float* y0a = (const float*)&Y0;
            const float* y2a = (const float*)&Y2;
            const float* pa  = (const float*)&Pv;
            const float* qa  = (const float*)&Qv;
#pragma unroll
            for (int i = 0; i < 4; ++i) {
                a[i][0]  += y0a[i] * w0.x;  a[i][1]  += y0a[i] * w0.y;
                a[i][2]  += y2a[i] * w1.x;  a[i][3]  += y2a[i] * w1.y;
                a[i][4]  += pa[i]  * w0.z;  a[i][5]  += qa[i]  * w0.w;
                a[i][6]  += pa[i]  * w0.w;  a[i][7]  += qa[i]  * w0.z;
                a[i][8]  += pa[i]  * w1.z;  a[i][9]  += qa[i]  * w1.w;
                a[i][10] += pa[i]  * w1.w;  a[i][11] += qa[i]  * w1.z;
            }
        }
        __syncthreads();
    }

    // combine accumulators to final complex G contributions (32 floats)
    float gv[32];
#pragma unroll
    for (int i = 0; i < 4; ++i) {
        gv[i * 8 + 0] = a[i][0];             // Re G[4g]
        gv[i * 8 + 1] = -a[i][1];            // Im G[4g]
        gv[i * 8 + 2] = a[i][4] - a[i][5];   // Re G[4g+1] = Pc - Qs
        gv[i * 8 + 3] = -(a[i][6] + a[i][7]);// Im G[4g+1] = -(Ps + Qc)
        gv[i * 8 + 4] = a[i][2];             // Re G[4g+2]
        gv[i * 8 + 5] = -a[i][3];
        gv[i * 8 + 6] = a[i][8] + a[i][9];   // Re G[4g+3] = Pc + Qs
        gv[i * 8 + 7] = a[i][11] - a[i][10]; // Im G[4g+3] = Qc - Ps
    }

    // cross-sub reduce via LDS (XOR-swizzled float4 to spread banks)
    float4* red = (float4*)y_s;              // [256][8] float4 = 32 KB
    float4* gvf = (float4*)gv;
    if (sub == 1) {
#pragma unroll
        for (int j = 0; j < 8; ++j) red[st * 8 + (j ^ (st & 7))] = gvf[j];
    }
    __syncthreads();
    if (sub == 0) {
        int slot = ((z * 16 + b) * 8 + h) * 2 + chunk;
        float4* gp = (float4*)(Gp + (size_t)slot * 4096);
#pragma unroll
        for (int j = 0; j < 8; ++j) {
            float4 r = red[st * 8 + (j ^ (st & 7))];
            float4 v = gvf[j];
            v.x += r.x; v.y += r.y; v.z += r.z; v.w += r.w;
            int i = j >> 1, half = j & 1;
            gp[(eg * 4 + i) * 32 + 2 * g + half] = v;
        }
    }
}

// ---------------------------------------------------------------------------
// Sum the 2 chunk slots -> Gq / Gk final [b][h][e][x] complex.
__global__ __launch_bounds__(256) void k_reduce(
    const float4* __restrict__ Gp, float4* __restrict__ Gq, float4* __restrict__ Gk)
{
    int gid = blockIdx.x * 256 + threadIdx.x;   // 131072
#pragma unroll
    for (int kk = 0; kk < 4; ++kk) {
        int f4 = gid + kk * 131072;             // 524288 float4 outputs
        int zbh = f4 >> 11, pos = f4 & 2047;
        const float4* s = Gp + (size_t)(zbh * 2) * 2048;
        float4 x0 = s[pos], x1 = s[2048 + pos];
        x0.x += x1.x; x0.y += x1.y; x0.z += x1.z; x0.w += x1.w;
        float4* dst = (zbh < 128) ? Gq : Gk;
        dst[(size_t)(zbh & 127) * 2048 + pos] = x0;
    }
}

// ---------------------------------------------------------------------------
// Per (b,h): freq-domain projection of q,k; S = Q^T K; tanh; U = T K.
__global__ __launch_bounds__(256) void k_core(
    const float2* __restrict__ Gq, const float2* __restrict__ Gk,
    const float* __restrict__ wqw, const float* __restrict__ wqb,
    const float* __restrict__ wkw, const float* __restrict__ wkb,
    const int* __restrict__ iq, const int* __restrict__ ikv,
    float2* __restrict__ U)
{
    int b = blockIdx.x, h = blockIdx.y;
    int tid = threadIdx.x;
    __shared__ float2 bufA[4096];
    __shared__ float2 Qf[4096];
    __shared__ float2 Kf[4096];
    __shared__ float  Wm[4096];
    __shared__ float  bias_s[64];
    __shared__ int    idx_s[64];

    size_t gb = (size_t)(b * 8 + h) * 4096;

    for (int z = 0; z < 2; ++z) {
        const float* Wsrc = z ? wkw : wqw;
        const float* bsrc = z ? wkb : wqb;
        const int*   isrc = z ? ikv : iq;
        const float2* Gsrc = (z ? Gk : Gq) + gb;
        float2* dst = z ? Kf : Qf;
        if (tid < 64) { bias_s[tid] = bsrc[tid]; idx_s[tid] = isrc[tid]; }
#pragma unroll
        for (int j = 0; j < 4; ++j)
            ((float4*)Wm)[tid + 256 * j] = ((const float4*)Wsrc)[tid + 256 * j];
#pragma unroll
        for (int j = 0; j < 8; ++j)
            ((float4*)bufA)[tid + 256 * j] = ((const float4*)Gsrc)[tid + 256 * j];
        __syncthreads();
        {
            int eg = tid >> 4, xg = tid & 15;
            float2 acc[4][4];
#pragma unroll
            for (int i = 0; i < 4; ++i)
#pragma unroll
                for (int j = 0; j < 4; ++j) acc[i][j] = make_float2(0.f, 0.f);
            for (int ep = 0; ep < 64; ++ep) {
                float wv[4]; float2 gvv[4];
#pragma unroll
                for (int i = 0; i < 4; ++i) wv[i] = Wm[(eg * 4 + i) * 64 + ep];
#pragma unroll
                for (int j = 0; j < 4; ++j) gvv[j] = bufA[ep * 64 + xg + 16 * j];
#pragma unroll
                for (int i = 0; i < 4; ++i)
#pragma unroll
                    for (int j = 0; j < 4; ++j) {
                        acc[i][j].x += wv[i] * gvv[j].x;
                        acc[i][j].y += wv[i] * gvv[j].y;
                    }
            }
#pragma unroll
            for (int j = 0; j < 4; ++j) {
                int x = xg + 16 * j;
                float bz = (idx_s[x] == 0) ? 2048.0f : 0.0f;
#pragma unroll
                for (int i = 0; i < 4; ++i) {
                    float2 v = acc[i][j];
                    v.x += bz * bias_s[eg * 4 + i];
                    dst[(eg * 4 + i) * 64 + x] = v;
                }
            }
        }
        __syncthreads();
    }

    {
        int xg = tid & 15, yg = tid >> 4;
        float2 acc[4][4];
#pragma unroll
        for (int i = 0; i < 4; ++i)
#pragma unroll
            for (int j = 0; j < 4; ++j) acc[i][j] = make_float2(0.f, 0.f);
        for (int e = 0; e < 64; ++e) {
            float2 qv[4], kv[4];
#pragma unroll
            for (int i = 0; i < 4; ++i) qv[i] = Qf[e * 64 + xg + 16 * i];
#pragma unroll
            for (int j = 0; j < 4; ++j) kv[j] = Kf[e * 64 + yg * 4 + j];
#pragma unroll
            for (int i = 0; i < 4; ++i)
#pragma unroll
                for (int j = 0; j < 4; ++j) {
                    acc[i][j].x += qv[i].x * kv[j].x - qv[i].y * kv[j].y;
                    acc[i][j].y += qv[i].x * kv[j].y + qv[i].y * kv[j].x;
                }
        }
#pragma unroll
        for (int i = 0; i < 4; ++i)
#pragma unroll
            for (int j = 0; j < 4; ++j)
                bufA[(yg * 4 + j) * 64 + xg + 16 * i] =
                    make_float2(tanhf(acc[i][j].x), tanhf(acc[i][j].y));
    }
    __syncthreads();

    {
        int xg = tid & 15, eg = tid >> 4;
        float2 acc[4][4];
#pragma unroll
        for (int i = 0; i < 4; ++i)
#pragma unroll
            for (int j = 0; j < 4; ++j) acc[i][j] = make_float2(0.f, 0.f);
        for (int y = 0; y < 64; ++y) {
            float2 kv[4], tv[4];
#pragma unroll
            for (int i = 0; i < 4; ++i) kv[i] = Kf[(eg * 4 + i) * 64 + y];
#pragma unroll
            for (int j = 0; j < 4; ++j) tv[j] = bufA[y * 64 + xg + 16 * j];
#pragma unroll
            for (int i = 0; i < 4; ++i)
#pragma unroll
                for (int j = 0; j < 4; ++j) {
                    acc[i][j].x += tv[j].x * kv[i].x - tv[j].y * kv[i].y;
                    acc[i][j].y += tv[j].x * kv[i].y + tv[j].y * kv[i].x;
                }
        }
        float2* Ud = U + gb;
#pragma unroll
        for (int i = 0; i < 4; ++i)
#pragma unroll
            for (int j = 0; j < 4; ++j)
                Ud[(eg * 4 + i) * 64 + xg + 16 * j] = acc[i][j];
    }
}

// ---------------------------------------------------------------------------
// Per (h,x): X[b,o] = sum_e U[b,e] wc[e,o]; fold irfft scales; A[b][h][o][x]=(P,Q).
__global__ __launch_bounds__(128) void k_apply_w(
    const float2* __restrict__ U, const float2* __restrict__ wc,
    const int* __restrict__ iq, float2* __restrict__ A)
{
    int x = blockIdx.x, h = blockIdx.y;
    int tid = threadIdx.x;
    __shared__ float2 wl[4096];
    __shared__ float2 ul[16][65];
    const float4* wsrc = (const float4*)(wc + (size_t)(h * 64 + x) * 4096);
#pragma unroll
    for (int j = 0; j < 16; ++j)
        ((float4*)wl)[tid + 128 * j] = wsrc[tid + 128 * j];
#pragma unroll
    for (int j = 0; j < 8; ++j) {
        int idx = tid + 128 * j;
        int bb = idx >> 6, e = idx & 63;
        ul[bb][e] = U[((size_t)(bb * 8 + h) * 64 + e) * 64 + x];
    }
    __syncthreads();
    int bb = tid >> 3, og = tid & 7;
    float2 acc[8];
#pragma unroll
    for (int j = 0; j < 8; ++j) acc[j] = make_float2(0.f, 0.f);
    for (int e = 0; e < 64; ++e) {
        float2 u = ul[bb][e];
#pragma unroll
        for (int j = 0; j < 8; ++j) {
            float2 wv = wl[e * 64 + og + 8 * j];
            acc[j].x += u.x * wv.x - u.y * wv.y;
            acc[j].y += u.x * wv.y + u.y * wv.x;
        }
    }
    int f = iq[x];
    bool dc = (f == 0) || (2 * f == Lseq);
    float cm = (dc ? 1.0f : 2.0f) * (1.0f / (2048.0f * 262144.0f));
    float2* Ad = A + (size_t)(bb * 8 + h) * 4096;
#pragma unroll
    for (int j = 0; j < 8; ++j) {
        int o = og + 8 * j;
        Ad[o * 64 + x] = make_float2(cm * acc[j].x, dc ? 0.0f : -cm * acc[j].y);
    }
}

// ---------------------------------------------------------------------------
// Radix-4 inverse: out[t'+512j] from U_r/V_r class sums.
// grid (tt:8, h, b), 512 thr: wave = o-slice of 8 (A reads wave-uniform),
// lane = t'. tw tile XOR-swizzled by row (2-way max conflicts).
__global__ __launch_bounds__(512) void k_irfft(
    const float2* __restrict__ A, const float* __restrict__ tw,
    float* __restrict__ out)
{
    int tt = blockIdx.x, h = blockIdx.y, b = blockIdx.z;
    int t0 = tt * 64;
    int tid = threadIdx.x;
    __shared__ float2 A_s[4096];        // [o][x] (P,Q)
    __shared__ float  tw_s[64][128];    // rows t', XOR-swizzled float4s
    const float4* asrc = (const float4*)(A + (size_t)(b * 8 + h) * 4096);
#pragma unroll
    for (int j = 0; j < 4; ++j)
        ((float4*)A_s)[tid + 512 * j] = asrc[tid + 512 * j];
    {
        int row = tid >> 3, c4b = (tid & 7) * 4;
        const float4* s = (const float4*)(tw + (size_t)(t0 + row) * 128);
        float4* drow = (float4*)&tw_s[row][0];
#pragma unroll
        for (int kk = 0; kk < 4; ++kk) {
            int c4 = c4b + kk;
            drow[c4 ^ (row & 31)] = s[c4];
        }
    }
    __syncthreads();
    int tl = tid & 63, ow = tid >> 6;    // o = ow*8 + i
    float U0[8], U1[8], V1[8], U2[8], U3[8], V3[8];
#pragma unroll
    for (int i = 0; i < 8; ++i) { U0[i]=U1[i]=V1[i]=U2[i]=U3[i]=V3[i]=0.f; }
    const float4* trow = (const float4*)&tw_s[tl][0];
    int sw = tl & 31;
#pragma unroll
    for (int g = 0; g < 16; ++g) {
        float4 w0 = trow[(2 * g) ^ sw];       // c(4g),s(4g),c(4g+1),s(4g+1)
        float4 w1 = trow[(2 * g + 1) ^ sw];   // c(4g+2),s(4g+2),c(4g+3),s(4g+3)
#pragma unroll
        for (int i = 0; i < 8; ++i) {
            const float4* ap = (const float4*)&A_s[(ow * 8 + i) * 64 + 4 * g];
            float4 a0 = ap[0];   // P0,Q0,P1,Q1
            float4 a1 = ap[1];   // P2,Q2,P3,Q3
            U0[i] += a0.x * w0.x + a0.y * w0.y;
            U1[i] += a0.z * w0.z + a0.w * w0.w;
            V1[i] += a0.w * w0.z - a0.z * w0.w;
            U2[i] += a1.x * w1.x + a1.y * w1.y;
            U3[i] += a1.z * w1.z + a1.w * w1.w;
            V3[i] += a1.w * w1.z - a1.z * w1.w;
        }
    }
    float* op = out + ((size_t)(b * 8 + h) * 64 + ow * 8) * Lseq + t0 + tl;
#pragma unroll
    for (int i = 0; i < 8; ++i) {
        float u0 = U0[i], u1 = U1[i], v1 = V1[i], u2 = U2[i], u3 = U3[i], v3 = V3[i];
        op[(size_t)i * Lseq +    0] = u0 + u1 + u2 + u3;
        op[(size_t)i * Lseq +  512] = u0 + v1 - u2 - v3;
        op[(size_t)i * Lseq + 1024] = u0 - u1 + u2 - u3;
        op[(size_t)i * Lseq + 1536] = u0 - v1 - u2 + v3;
    }
}

// ---------------------------------------------------------------------------
extern "C" void kernel_launch(void* const* d_in, const int* in_sizes, int n_in,
                              void* d_out, int out_size, void* d_ws, size_t ws_size,
                              hipStream_t stream)
{
    const float* q    = (const float*)d_in[0];
    const float* k    = (const float*)d_in[1];
    const float* wq_w = (const float*)d_in[3];
    const float* wq_b = (const float*)d_in[4];
    const float* wk_w = (const float*)d_in[5];
    const float* wk_b = (const float*)d_in[6];
    const float* w1   = (const float*)d_in[9];
    const float* w2   = (const float*)d_in[10];
    const int*   iq   = (const int*)d_in[11];
    const int*   ikv  = (const int*)d_in[12];
    float* out = (float*)d_out;

    char* ws = (char*)d_ws;
    float2* twq = (float2*)(ws + OFF_TWQ);
    float2* twk = (float2*)(ws + OFF_TWK);
    float2* Gq  = (float2*)(ws + OFF_GQ);
    float2* Gk  = (float2*)(ws + OFF_GK);
    float2* Uw  = (float2*)(ws + OFF_U);
    float2* Aw  = (float2*)(ws + OFF_A);
    float2* Gp  = (float2*)(ws + OFF_GP);
    float2* wc  = (float2*)(ws + OFF_WC);

    k_twiddle<<<128, 256, 0, stream>>>(iq, ikv, twq, twk);
    k_dft<<<dim3(16, 8, 4), 512, 0, stream>>>(q, k, (const float*)twq,
                                              (const float*)twk, Gp);
    k_reduce<<<512, 256, 0, stream>>>((const float4*)Gp, (float4*)Gq, (float4*)Gk);
    k_core<<<dim3(16, 8), 256, 0, stream>>>(Gq, Gk, wq_w, wq_b, wk_w, wk_b,
                                            iq, ikv, Uw);
    k_wtrans<<<dim3(8, 64), 256, 0, stream>>>(w1, w2, wc);
    k_apply_w<<<dim3(64, 8), 128, 0, stream>>>(Uw, wc, iq, Aw);
    k_irfft<<<dim3(8, 8, 16), 512, 0, stream>>>(Aw, (const float*)twq, out);
}